// Round 1
// 3931.439 us; speedup vs baseline: 5.4656x; 5.4656x over previous
//
#include <hip/hip_runtime.h>

typedef __attribute__((ext_vector_type(8))) short short8;
typedef __attribute__((ext_vector_type(4))) float floatx4;
typedef unsigned short u16;
typedef __attribute__((ext_vector_type(4))) unsigned short u16x4;

#define B_ 128
#define S_ 512
#define D_ 256
#define H_ 512
#define O_ 256

__device__ __forceinline__ u16 f2bf(float f) {
  union { float f; unsigned u; } v; v.f = f;
  unsigned r = v.u + 0x7fffu + ((v.u >> 16) & 1u);
  return (u16)(r >> 16);
}
__device__ __forceinline__ float sigf(float x) { return 1.f / (1.f + __expf(-x)); }
__device__ __forceinline__ float tanhf_fast(float x) { return 1.f - 2.f / (__expf(2.f * x) + 1.f); }

// 16B fragment load that bypasses L1/L2 (device-coherent, reads the MALL).
// RELAXED+AGENT atomics emit flagged loads with NO cache-maintenance fences.
__device__ __forceinline__ short8 ld_frag_agent(const u16* p) {
  union { unsigned long long u[2]; short8 v; } w;
  unsigned long long* q = (unsigned long long*)p;
  w.u[0] = __hip_atomic_load(q,     __ATOMIC_RELAXED, __HIP_MEMORY_SCOPE_AGENT);
  w.u[1] = __hip_atomic_load(q + 1, __ATOMIC_RELAXED, __HIP_MEMORY_SCOPE_AGENT);
  return w.v;
}

// ---------------- conversion kernels ----------------
__global__ __launch_bounds__(256) void cvt_bf16_vec(const float* __restrict__ in,
                                                    u16* __restrict__ out, int n4) {
  int i = blockIdx.x * 256 + threadIdx.x;
  if (i < n4) {
    const float4 v = ((const float4*)in)[i];
    u16x4 o;
    o.x = f2bf(v.x); o.y = f2bf(v.y); o.z = f2bf(v.z); o.w = f2bf(v.w);
    ((u16x4*)out)[i] = o;
  }
}

// out[c][r] = in[r][c]; in is [R][C] f32, out is [C][R] bf16
__global__ __launch_bounds__(256) void transpose_cvt(const float* __restrict__ in,
                                                     u16* __restrict__ out, int R, int C) {
  int idx = blockIdx.x * 256 + threadIdx.x;
  if (idx < R * C) {
    int r = idx % R, c = idx / R;
    out[idx] = f2bf(in[(size_t)r * C + c]);
  }
}

// ---------------- persistent scan kernel ----------------
// grid = 256 WGs x 320 threads (5 waves).  group g = blockIdx&7 (XCD swizzle),
// member m = blockIdx>>3.  group handles batches [16g,16g+16); member handles
// hidden units [16m,16m+16).  waves 0..3 = gates f,i,o,g; wave 4 = c_st.
// LDS-resident weight slices.  Cross-WG state exchange (h, c both bf16) goes
// through RELAXED agent-scope atomics = write-through/bypass-L2 (MALL-coherent)
// so NO buffer_wbl2 / buffer_inv L2 sweeps per step.  Own-unit cell state is a
// private f32 register (thread<->unit mapping is fixed across steps).
#define PU 520   // padded K-stride for K=512 tiles (bank-conflict: 2-way, free)
#define PX 264   // padded K-stride for K=256 tiles
#define SCAN_SMEM ((size_t)(4*16*PU + 4*16*PX + 16*PU) * 2 + (size_t)5*272*4)

__global__ __launch_bounds__(320, 2) void tlstm_scan(
    const u16* __restrict__ xbf,      // [B,S,D] bf16
    const float* __restrict__ tdiff,  // [B,S]
    const u16* __restrict__ UallT,    // [4H][H]  bf16 (B^T layout)
    const u16* __restrict__ WallT,    // [4H][D]
    const u16* __restrict__ WdT,      // [H][H]
    const float* __restrict__ b_all, const float* __restrict__ b_u,
    const float* __restrict__ b_d,
    u16* __restrict__ h_state,        // [2][B][H] bf16 ping-pong (exchange)
    u16* __restrict__ c_state,        // [2][B][H] bf16 ping-pong (exchange)
    unsigned* __restrict__ bar,       // 8 counters, 256B apart
    float* __restrict__ d_hs, float* __restrict__ d_cs,
    u16* __restrict__ hs_bf)          // [B,S,H] bf16 (gemm2 input)
{
  extern __shared__ char smem[];
  u16* ldsU = (u16*)smem;                 // [4*16][PU]
  u16* ldsX = ldsU + 4 * 16 * PU;         // [4*16][PX]
  u16* ldsC = ldsX + 4 * 16 * PX;         // [16][PU]
  float* ldsP = (float*)(ldsC + 16 * PU); // [5][16*17]

  const int g = blockIdx.x & 7, mem = blockIdx.x >> 3;
  const int B0 = g * 16, U0 = mem * 16;
  const int tid = threadIdx.x;

  // ---- stage weight slices into LDS (once) ----
  for (int i = tid; i < 4 * 16 * 64; i += 320) {       // U tiles: 4 gates x 16 units x 512K
    int w = i >> 10, r = i & 1023, n = r >> 6, kb = r & 63;
    *(short8*)(ldsU + (w * 16 + n) * PU + kb * 8) =
        *(const short8*)(UallT + (size_t)(w * 512 + U0 + n) * 512 + kb * 8);
  }
  for (int i = tid; i < 4 * 16 * 32; i += 320) {       // W_all tiles: K=256
    int w = i >> 9, r = i & 511, n = r >> 5, kb = r & 31;
    *(short8*)(ldsX + (w * 16 + n) * PX + kb * 8) =
        *(const short8*)(WallT + (size_t)(w * 512 + U0 + n) * 256 + kb * 8);
  }
  for (int i = tid; i < 16 * 64; i += 320) {           // W_d tile
    int n = i >> 6, kb = i & 63;
    *(short8*)(ldsC + n * PU + kb * 8) =
        *(const short8*)(WdT + (size_t)(U0 + n) * 512 + kb * 8);
  }

  // ---- per-thread elementwise constants ----
  const int em = tid >> 4, eu = tid & 15;  // valid for tid<256
  const int ug = U0 + eu;
  const int ebb = B0 + em;
  float bf_ = 0.f, bi_ = 0.f, bo_ = 0.f, bg_ = 0.f, bd_ = 0.f;
  if (tid < 256) {
    bf_ = b_all[ug] + b_u[ug];
    bi_ = b_all[512 + ug] + b_u[512 + ug];
    bo_ = b_all[1024 + ug] + b_u[1024 + ug];
    bg_ = b_all[1536 + ug] + b_u[1536 + ug];
    bd_ = b_d[ug];
  }
  const int wv = tid >> 6, lane = tid & 63, lm = lane & 15, quad = lane >> 4;
  float creg = 0.f;   // private cell state for (ebb, ug), tid<256
  __syncthreads();

  for (int s = 0; s < S_; ++s) {
    const u16* hcur = h_state + (size_t)(s & 1) * B_ * H_;
    const u16* ccur = c_state + (size_t)(s & 1) * B_ * H_;
    u16* hnxt = h_state + (size_t)((s + 1) & 1) * B_ * H_;
    u16* cnxt = c_state + (size_t)((s + 1) & 1) * B_ * H_;

    floatx4 acc = {0.f, 0.f, 0.f, 0.f};
    if (wv < 4) {
      // gate wave: acc = h@U[:,cols] + x@W_all[:,cols]
      short8 ha[16], xa[8];
      const u16* hrow = hcur + (size_t)(B0 + lm) * H_ + quad * 8;
#pragma unroll
      for (int it = 0; it < 16; ++it) ha[it] = ld_frag_agent(hrow + it * 32);
      const u16* xrow = xbf + ((size_t)(B0 + lm) * S_ + s) * D_ + quad * 8;
#pragma unroll
      for (int it = 0; it < 8; ++it) xa[it] = *(const short8*)(xrow + it * 32);
      const u16* bU = ldsU + (wv * 16 + lm) * PU + quad * 8;
#pragma unroll
      for (int it = 0; it < 16; ++it)
        acc = __builtin_amdgcn_mfma_f32_16x16x32_bf16(ha[it], *(const short8*)(bU + it * 32), acc, 0, 0, 0);
      const u16* bX = ldsX + (wv * 16 + lm) * PX + quad * 8;
#pragma unroll
      for (int it = 0; it < 8; ++it)
        acc = __builtin_amdgcn_mfma_f32_16x16x32_bf16(xa[it], *(const short8*)(bX + it * 32), acc, 0, 0, 0);
    } else {
      // c_st wave: acc = c@W_d[:,cols]   (c exchanged as bf16 already)
      short8 ca[16];
      const u16* crow = ccur + (size_t)(B0 + lm) * H_ + quad * 8;
#pragma unroll
      for (int it = 0; it < 16; ++it) ca[it] = ld_frag_agent(crow + it * 32);
      const u16* bC = ldsC + lm * PU + quad * 8;
#pragma unroll
      for (int it = 0; it < 16; ++it)
        acc = __builtin_amdgcn_mfma_f32_16x16x32_bf16(ca[it], *(const short8*)(bC + it * 32), acc, 0, 0, 0);
    }
    // pre-activations -> LDS  (C-frag: col=lane&15, row=quad*4+reg)
    {
      float* P = ldsP + wv * 272;
#pragma unroll
      for (int r = 0; r < 4; ++r) P[(quad * 4 + r) * 17 + lm] = acc[r];
    }
    __syncthreads();

    if (tid < 256) {
      const float f   = ldsP[0 * 272 + em * 17 + eu];
      const float ii  = ldsP[1 * 272 + em * 17 + eu];
      const float oo  = ldsP[2 * 272 + em * 17 + eu];
      const float ggv = ldsP[3 * 272 + em * 17 + eu];
      const float csp = ldsP[4 * 272 + em * 17 + eu];
      const float tt = tdiff[(size_t)ebb * S_ + s];
      const float cst = sigf(csp + bd_);
      const float cadj = creg - cst + cst * tt;
      const float fv = sigf(f + bf_), iv = sigf(ii + bi_), ov = sigf(oo + bo_);
      const float gv = tanhf_fast(ggv + bg_);
      const float ct = fv * cadj + iv * gv;
      const float ht = ov * tanhf_fast(ct);
      creg = ct;
      const size_t oidx = ((size_t)ebb * S_ + s) * H_ + ug;
      d_hs[oidx] = ht;
      d_cs[oidx] = ct;
      const unsigned hb = (unsigned)f2bf(ht);
      const unsigned cb = (unsigned)f2bf(ct);
      hs_bf[oidx] = (u16)hb;
      // pack (even,odd) unit pair into one 4B word via lane shuffle, then
      // write-through (agent-scope relaxed) so it is MALL-visible on retire.
      const unsigned hn = (unsigned)__shfl_xor((int)hb, 1);
      const unsigned cn = (unsigned)__shfl_xor((int)cb, 1);
      if (!(eu & 1)) {
        const size_t wi = ((size_t)ebb * H_ + ug) >> 1;
        __hip_atomic_store((unsigned*)hnxt + wi, hb | (hn << 16),
                           __ATOMIC_RELAXED, __HIP_MEMORY_SCOPE_AGENT);
        __hip_atomic_store((unsigned*)cnxt + wi, cb | (cn << 16),
                           __ATOMIC_RELAXED, __HIP_MEMORY_SCOPE_AGENT);
      }
    }

    // ---- group barrier (32 WGs). No fences: the s_waitcnt vmcnt(0) the
    // compiler emits before s_barrier drains the write-through stores to the
    // MALL; the counter RMW and all exchange loads also execute at the MALL.
    __syncthreads();
    if (tid == 0) {
      __hip_atomic_fetch_add(&bar[g * 64], 1u, __ATOMIC_RELAXED, __HIP_MEMORY_SCOPE_AGENT);
      const unsigned tgt = 32u * (unsigned)(s + 1);
      while (__hip_atomic_load(&bar[g * 64], __ATOMIC_RELAXED, __HIP_MEMORY_SCOPE_AGENT) < tgt)
        __builtin_amdgcn_s_sleep(2);
    }
    __syncthreads();
  }
}

// ---------------- output GEMM: out = hs_bf16 @ W_out + b_out ----------------
// M=65536, N=256, K=512.  WG 256 thr = 2x2 waves, each wave 32x32.
__global__ __launch_bounds__(256, 4) void gemm2(const u16* __restrict__ A,
                                                const u16* __restrict__ Bt,
                                                const float* __restrict__ bias,
                                                float* __restrict__ C) {
  const int K = 512, N = 256;
  const int wave = threadIdx.x >> 6, lane = threadIdx.x & 63;
  const int wm = wave >> 1, wn = wave & 1;
  const int lm = lane & 15, quad = lane >> 4;
  const int Mb = blockIdx.x * 64 + wm * 32;
  const int Nb = blockIdx.y * 64 + wn * 32;
  const u16* a0 = A + (size_t)(Mb + lm) * K + quad * 8;
  const u16* a1 = a0 + (size_t)16 * K;
  const u16* b0 = Bt + (size_t)(Nb + lm) * K + quad * 8;
  const u16* b1 = b0 + (size_t)16 * K;
  floatx4 acc00 = {0,0,0,0}, acc01 = {0,0,0,0}, acc10 = {0,0,0,0}, acc11 = {0,0,0,0};
#pragma unroll 4
  for (int k = 0; k < K; k += 32) {
    short8 av0 = *(const short8*)(a0 + k);
    short8 av1 = *(const short8*)(a1 + k);
    short8 bv0 = *(const short8*)(b0 + k);
    short8 bv1 = *(const short8*)(b1 + k);
    acc00 = __builtin_amdgcn_mfma_f32_16x16x32_bf16(av0, bv0, acc00, 0, 0, 0);
    acc01 = __builtin_amdgcn_mfma_f32_16x16x32_bf16(av0, bv1, acc01, 0, 0, 0);
    acc10 = __builtin_amdgcn_mfma_f32_16x16x32_bf16(av1, bv0, acc10, 0, 0, 0);
    acc11 = __builtin_amdgcn_mfma_f32_16x16x32_bf16(av1, bv1, acc11, 0, 0, 0);
  }
  const float bia0 = bias[Nb + lm], bia1 = bias[Nb + 16 + lm];
#pragma unroll
  for (int r = 0; r < 4; ++r) {
    const int row0 = Mb + quad * 4 + r;
    C[(size_t)row0 * N + Nb + lm]            = acc00[r] + bia0;
    C[(size_t)row0 * N + Nb + 16 + lm]       = acc01[r] + bia1;
    C[(size_t)(row0 + 16) * N + Nb + lm]     = acc10[r] + bia0;
    C[(size_t)(row0 + 16) * N + Nb + 16 + lm] = acc11[r] + bia1;
  }
}

// ---------------- host ----------------
extern "C" void kernel_launch(void* const* d_in, const int* in_sizes, int n_in,
                              void* d_out, int out_size, void* d_ws, size_t ws_size,
                              hipStream_t stream) {
  const float* inputs = (const float*)d_in[0];
  const float* tdiff  = (const float*)d_in[1];
  // d_in[2] = seq_lens : unused by the reference
  const float* W_all = (const float*)d_in[3];
  const float* b_all = (const float*)d_in[4];
  const float* U_all = (const float*)d_in[5];
  const float* b_u   = (const float*)d_in[6];
  const float* W_d   = (const float*)d_in[7];
  const float* b_d   = (const float*)d_in[8];
  const float* W_out = (const float*)d_in[9];
  const float* b_out = (const float*)d_in[10];

  float* out = (float*)d_out;
  float* d_outputs = out;                                   // [B,S,O]
  float* d_hs = out + (size_t)B_ * S_ * O_;                 // [B,S,H]
  float* d_cs = d_hs + (size_t)B_ * S_ * H_;                // [B,S,H]

  char* ws = (char*)d_ws;
  size_t off = 0;
  auto alloc = [&](size_t bytes) {
    char* p = ws + off;
    off += (bytes + 255) & ~(size_t)255;
    return p;
  };
  u16* xbf      = (u16*)alloc((size_t)B_ * S_ * D_ * 2);        // 32 MB
  u16* hs_bf    = (u16*)alloc((size_t)B_ * S_ * H_ * 2);        // 64 MB
  u16* UallT    = (u16*)alloc((size_t)2048 * 512 * 2);
  u16* WallT    = (u16*)alloc((size_t)2048 * 256 * 2);
  u16* WdT      = (u16*)alloc((size_t)512 * 512 * 2);
  u16* WoutT    = (u16*)alloc((size_t)256 * 512 * 2);
  u16* h_state  = (u16*)alloc((size_t)2 * B_ * H_ * 2);
  u16* c_state  = (u16*)alloc((size_t)2 * B_ * H_ * 2);
  unsigned* bar = (unsigned*)alloc(4096);

  // zero initial state + barrier counters (ws is re-poisoned before every call)
  hipMemsetAsync(h_state, 0, (size_t)2 * B_ * H_ * 2, stream);
  hipMemsetAsync(c_state, 0, (size_t)2 * B_ * H_ * 2, stream);
  hipMemsetAsync(bar, 0, 4096, stream);

  cvt_bf16_vec<<<(B_ * S_ * D_ / 4 + 255) / 256, 256, 0, stream>>>(inputs, xbf, B_ * S_ * D_ / 4);
  transpose_cvt<<<(256 * 2048 + 255) / 256, 256, 0, stream>>>(W_all, WallT, 256, 2048);
  transpose_cvt<<<(512 * 2048 + 255) / 256, 256, 0, stream>>>(U_all, UallT, 512, 2048);
  transpose_cvt<<<(512 * 512 + 255) / 256, 256, 0, stream>>>(W_d, WdT, 512, 512);
  transpose_cvt<<<(512 * 256 + 255) / 256, 256, 0, stream>>>(W_out, WoutT, 512, 256);

  (void)hipFuncSetAttribute((const void*)tlstm_scan,
                            hipFuncAttributeMaxDynamicSharedMemorySize, (int)SCAN_SMEM);
  tlstm_scan<<<256, 320, SCAN_SMEM, stream>>>(xbf, tdiff, UallT, WallT, WdT,
                                              b_all, b_u, b_d, h_state, c_state,
                                              bar, d_hs, d_cs, hs_bf);
  gemm2<<<dim3(B_ * S_ / 64, O_ / 64), 256, 0, stream>>>(hs_bf, WoutT, b_out, d_outputs);
}

// Round 3
// 2295.299 us; speedup vs baseline: 9.3615x; 1.7128x over previous
//
#include <hip/hip_runtime.h>

typedef __attribute__((ext_vector_type(8))) short short8;
typedef __attribute__((ext_vector_type(4))) float floatx4;
typedef unsigned short u16;
typedef __attribute__((ext_vector_type(4))) unsigned short u16x4;

#define B_ 128
#define S_ 512
#define D_ 256
#define H_ 512
#define O_ 256

__device__ __forceinline__ u16 f2bf(float f) {
  union { float f; unsigned u; } v; v.f = f;
  unsigned r = v.u + 0x7fffu + ((v.u >> 16) & 1u);
  return (u16)(r >> 16);
}
__device__ __forceinline__ float sigf(float x) { return 1.f / (1.f + __expf(-x)); }
__device__ __forceinline__ float tanhf_fast(float x) { return 1.f - 2.f / (__expf(2.f * x) + 1.f); }

// 8B load that bypasses L1/L2 (device-coherent, served by the MALL).
// RELAXED+AGENT atomics emit flagged loads with NO cache-maintenance fences.
__device__ __forceinline__ unsigned long long ld_u64_agent(const unsigned long long* p) {
  return __hip_atomic_load(p, __ATOMIC_RELAXED, __HIP_MEMORY_SCOPE_AGENT);
}

// ---------------- conversion kernels ----------------
__global__ __launch_bounds__(256) void cvt_bf16_vec(const float* __restrict__ in,
                                                    u16* __restrict__ out, int n4) {
  int i = blockIdx.x * 256 + threadIdx.x;
  if (i < n4) {
    const float4 v = ((const float4*)in)[i];
    u16x4 o;
    o.x = f2bf(v.x); o.y = f2bf(v.y); o.z = f2bf(v.z); o.w = f2bf(v.w);
    ((u16x4*)out)[i] = o;
  }
}

// out[c][r] = in[r][c]; in is [R][C] f32, out is [C][R] bf16
__global__ __launch_bounds__(256) void transpose_cvt(const float* __restrict__ in,
                                                     u16* __restrict__ out, int R, int C) {
  int idx = blockIdx.x * 256 + threadIdx.x;
  if (idx < R * C) {
    int r = idx % R, c = idx / R;
    out[idx] = f2bf(in[(size_t)r * C + c]);
  }
}

// ---------------- persistent scan kernel ----------------
// grid = 256 WGs x 320 threads (5 waves).  group g = blockIdx&7, member m =
// blockIdx>>3.  group handles batches [16g,16g+16); member handles hidden
// units [16m,16m+16).  waves 0..3 = gates f,i,o,g; wave 4 = c_st.
// Exchange (h, c bf16) goes through RELAXED agent-scope atomics (MALL-coherent,
// no L2 sweeps).  Per step each WG stages the 16x512 h-slab and c-slab into
// LDS ONCE (tid<256, 16 qwords each), so the 4 gate waves read A-fragments
// from LDS instead of re-reading the MALL 4x.  x-fragments for step s+1 are
// register-prefetched before the barrier; the x MFMA chain runs while the
// slab loads are in flight.
#define PU 520   // padded K-stride for K=512 tiles (2-way bank alias: free)
#define PX 264   // padded K-stride for K=256 tiles
#define SCAN_SMEM ((size_t)(4*16*PU + 4*16*PX + 3*16*PU) * 2 + (size_t)5*272*4)

__global__ __launch_bounds__(320, 1) void tlstm_scan(
    const u16* __restrict__ xbf,      // [B,S,D] bf16
    const float* __restrict__ tdiff,  // [B,S]
    const u16* __restrict__ UallT,    // [4H][H]  bf16 (B^T layout)
    const u16* __restrict__ WallT,    // [4H][D]
    const u16* __restrict__ WdT,      // [H][H]
    const float* __restrict__ b_all, const float* __restrict__ b_u,
    const float* __restrict__ b_d,
    u16* __restrict__ h_state,        // [2][B][H] bf16 ping-pong (exchange)
    u16* __restrict__ c_state,        // [2][B][H] bf16 ping-pong (exchange)
    unsigned* __restrict__ bar,       // 8 counters, 256B apart
    float* __restrict__ d_hs, float* __restrict__ d_cs,
    u16* __restrict__ hs_bf)          // [B,S,H] bf16 (gemm2 input)
{
  extern __shared__ char smem[];
  u16* ldsU  = (u16*)smem;                 // [4*16][PU]
  u16* ldsX  = ldsU + 4 * 16 * PU;         // [4*16][PX]
  u16* ldsC  = ldsX + 4 * 16 * PX;         // [16][PU]  W_d slice
  u16* ldsH  = ldsC + 16 * PU;             // [16][PU]  h slab (staged per step)
  u16* ldsC2 = ldsH + 16 * PU;             // [16][PU]  c slab (staged per step)
  float* ldsP = (float*)(ldsC2 + 16 * PU); // [5][16*17]

  const int g = blockIdx.x & 7, mem = blockIdx.x >> 3;
  const int B0 = g * 16, U0 = mem * 16;
  const int tid = threadIdx.x;

  // ---- stage weight slices into LDS (once) ----
  for (int i = tid; i < 4 * 16 * 64; i += 320) {       // U tiles: 4 gates x 16 units x 512K
    int w = i >> 10, r = i & 1023, n = r >> 6, kb = r & 63;
    *(short8*)(ldsU + (w * 16 + n) * PU + kb * 8) =
        *(const short8*)(UallT + (size_t)(w * 512 + U0 + n) * 512 + kb * 8);
  }
  for (int i = tid; i < 4 * 16 * 32; i += 320) {       // W_all tiles: K=256
    int w = i >> 9, r = i & 511, n = r >> 5, kb = r & 31;
    *(short8*)(ldsX + (w * 16 + n) * PX + kb * 8) =
        *(const short8*)(WallT + (size_t)(w * 512 + U0 + n) * 256 + kb * 8);
  }
  for (int i = tid; i < 16 * 64; i += 320) {           // W_d tile
    int n = i >> 6, kb = i & 63;
    *(short8*)(ldsC + n * PU + kb * 8) =
        *(const short8*)(WdT + (size_t)(U0 + n) * 512 + kb * 8);
  }

  // ---- per-thread elementwise constants ----
  const int em = tid >> 4, eu = tid & 15;  // valid for tid<256
  const int ug = U0 + eu;
  const int ebb = B0 + em;
  float bf_ = 0.f, bi_ = 0.f, bo_ = 0.f, bg_ = 0.f, bd_ = 0.f;
  if (tid < 256) {
    bf_ = b_all[ug] + b_u[ug];
    bi_ = b_all[512 + ug] + b_u[512 + ug];
    bo_ = b_all[1024 + ug] + b_u[1024 + ug];
    bg_ = b_all[1536 + ug] + b_u[1536 + ug];
    bd_ = b_d[ug];
  }
  const int wv = tid >> 6, lane = tid & 63, lm = lane & 15, quad = lane >> 4;
  float creg = 0.f;   // private cell state for (ebb, ug), tid<256

  // prefetch x fragments for step 0
  short8 pxa[8];
  if (wv < 4) {
    const u16* xrow = xbf + ((size_t)(B0 + lm) * S_ + 0) * D_ + quad * 8;
#pragma unroll
    for (int it = 0; it < 8; ++it) pxa[it] = *(const short8*)(xrow + it * 32);
  }
  __syncthreads();

  for (int s = 0; s < S_; ++s) {
    const u16* hcur = h_state + (size_t)(s & 1) * B_ * H_;
    const u16* ccur = c_state + (size_t)(s & 1) * B_ * H_;
    u16* hnxt = h_state + (size_t)((s + 1) & 1) * B_ * H_;
    u16* cnxt = c_state + (size_t)((s + 1) & 1) * B_ * H_;

    // ---- issue slab loads (h + c, 16 qwords/thread, coalesced) ----
    // batch row = 512 bf16 = 128 qwords; group slab starts at qword B0*128.
    unsigned long long hq[16];
    if (tid < 256) {
      const unsigned long long* hsrc = (const unsigned long long*)hcur + (size_t)B0 * 128;
      const unsigned long long* csrc = (const unsigned long long*)ccur + (size_t)B0 * 128;
#pragma unroll
      for (int k = 0; k < 16; ++k) {
        const int qq = tid + 256 * (k & 7);            // 0..2047
        hq[k] = ld_u64_agent(((k < 8) ? hsrc : csrc) + qq);
      }
    }

    // ---- x-part MFMA chain while slab loads are in flight ----
    floatx4 accx = {0.f, 0.f, 0.f, 0.f};
    if (wv < 4) {
      const u16* bX = ldsX + (wv * 16 + lm) * PX + quad * 8;
#pragma unroll
      for (int it = 0; it < 8; ++it)
        accx = __builtin_amdgcn_mfma_f32_16x16x32_bf16(pxa[it], *(const short8*)(bX + it * 32), accx, 0, 0, 0);
    }

    // ---- write slabs to LDS ----
    if (tid < 256) {
#pragma unroll
      for (int k = 0; k < 16; ++k) {
        const int qq = tid + 256 * (k & 7);
        const int row = qq >> 7, c8 = qq & 127;
        *(unsigned long long*)(((k < 8) ? ldsH : ldsC2) + row * PU + c8 * 4) = hq[k];
      }
    }
    __syncthreads();

    // ---- h-part (gate waves) / c-part (wave 4), two interleaved chains ----
    floatx4 a0 = {0.f, 0.f, 0.f, 0.f}, a1 = {0.f, 0.f, 0.f, 0.f};
    if (wv < 4) {
      const u16* arow = ldsH + lm * PU + quad * 8;
      const u16* bU = ldsU + (wv * 16 + lm) * PU + quad * 8;
#pragma unroll
      for (int it = 0; it < 8; ++it) {
        a0 = __builtin_amdgcn_mfma_f32_16x16x32_bf16(*(const short8*)(arow + it * 32),
                                                     *(const short8*)(bU + it * 32), a0, 0, 0, 0);
        a1 = __builtin_amdgcn_mfma_f32_16x16x32_bf16(*(const short8*)(arow + (it + 8) * 32),
                                                     *(const short8*)(bU + (it + 8) * 32), a1, 0, 0, 0);
      }
    } else {
      const u16* arow = ldsC2 + lm * PU + quad * 8;
      const u16* bC = ldsC + lm * PU + quad * 8;
#pragma unroll
      for (int it = 0; it < 8; ++it) {
        a0 = __builtin_amdgcn_mfma_f32_16x16x32_bf16(*(const short8*)(arow + it * 32),
                                                     *(const short8*)(bC + it * 32), a0, 0, 0, 0);
        a1 = __builtin_amdgcn_mfma_f32_16x16x32_bf16(*(const short8*)(arow + (it + 8) * 32),
                                                     *(const short8*)(bC + (it + 8) * 32), a1, 0, 0, 0);
      }
    }
    // pre-activations -> LDS  (C-frag: col=lane&15, row=quad*4+reg)
    {
      float* P = ldsP + wv * 272;
#pragma unroll
      for (int r = 0; r < 4; ++r)
        P[(quad * 4 + r) * 17 + lm] = accx[r] + a0[r] + a1[r];
    }
    __syncthreads();

    if (tid < 256) {
      const float f   = ldsP[0 * 272 + em * 17 + eu];
      const float ii  = ldsP[1 * 272 + em * 17 + eu];
      const float oo  = ldsP[2 * 272 + em * 17 + eu];
      const float ggv = ldsP[3 * 272 + em * 17 + eu];
      const float csp = ldsP[4 * 272 + em * 17 + eu];
      const float tt = tdiff[(size_t)ebb * S_ + s];
      const float cst = sigf(csp + bd_);
      const float cadj = creg - cst + cst * tt;
      const float fv = sigf(f + bf_), iv = sigf(ii + bi_), ov = sigf(oo + bo_);
      const float gv = tanhf_fast(ggv + bg_);
      const float ct = fv * cadj + iv * gv;
      const float ht = ov * tanhf_fast(ct);
      creg = ct;
      const size_t oidx = ((size_t)ebb * S_ + s) * H_ + ug;
      d_hs[oidx] = ht;
      d_cs[oidx] = ct;
      const unsigned hb = (unsigned)f2bf(ht);
      const unsigned cb = (unsigned)f2bf(ct);
      hs_bf[oidx] = (u16)hb;
      // pack (even,odd) unit pair into one 4B word via lane shuffle, then
      // write-through (agent-scope relaxed) so it is MALL-visible on retire.
      const unsigned hn = (unsigned)__shfl_xor((int)hb, 1);
      const unsigned cn = (unsigned)__shfl_xor((int)cb, 1);
      if (!(eu & 1)) {
        const size_t wi = ((size_t)ebb * H_ + ug) >> 1;
        __hip_atomic_store((unsigned*)hnxt + wi, hb | (hn << 16),
                           __ATOMIC_RELAXED, __HIP_MEMORY_SCOPE_AGENT);
        __hip_atomic_store((unsigned*)cnxt + wi, cb | (cn << 16),
                           __ATOMIC_RELAXED, __HIP_MEMORY_SCOPE_AGENT);
      }
    }

    // ---- prefetch x fragments for step s+1 (independent of h) ----
    if (wv < 4) {
      const int sn = (s + 1 < S_) ? s + 1 : s;
      const u16* xrow = xbf + ((size_t)(B0 + lm) * S_ + sn) * D_ + quad * 8;
#pragma unroll
      for (int it = 0; it < 8; ++it) pxa[it] = *(const short8*)(xrow + it * 32);
    }

    // ---- group barrier (32 WGs). No fences: the s_waitcnt vmcnt(0) the
    // compiler emits before s_barrier drains the write-through stores to the
    // MALL; the counter RMW and all exchange loads also execute at the MALL.
    __syncthreads();
    if (tid == 0) {
      __hip_atomic_fetch_add(&bar[g * 64], 1u, __ATOMIC_RELAXED, __HIP_MEMORY_SCOPE_AGENT);
      const unsigned tgt = 32u * (unsigned)(s + 1);
      while (__hip_atomic_load(&bar[g * 64], __ATOMIC_RELAXED, __HIP_MEMORY_SCOPE_AGENT) < tgt)
        __builtin_amdgcn_s_sleep(2);
    }
    __syncthreads();
  }
}

// ---------------- output GEMM: out = hs_bf16 @ W_out + b_out ----------------
// M=65536, N=256, K=512.  WG 256 thr = 2x2 waves, each wave 32x32.
__global__ __launch_bounds__(256, 4) void gemm2(const u16* __restrict__ A,
                                                const u16* __restrict__ Bt,
                                                const float* __restrict__ bias,
                                                float* __restrict__ C) {
  const int K = 512, N = 256;
  const int wave = threadIdx.x >> 6, lane = threadIdx.x & 63;
  const int wm = wave >> 1, wn = wave & 1;
  const int lm = lane & 15, quad = lane >> 4;
  const int Mb = blockIdx.x * 64 + wm * 32;
  const int Nb = blockIdx.y * 64 + wn * 32;
  const u16* a0 = A + (size_t)(Mb + lm) * K + quad * 8;
  const u16* a1 = a0 + (size_t)16 * K;
  const u16* b0 = Bt + (size_t)(Nb + lm) * K + quad * 8;
  const u16* b1 = b0 + (size_t)16 * K;
  floatx4 acc00 = {0,0,0,0}, acc01 = {0,0,0,0}, acc10 = {0,0,0,0}, acc11 = {0,0,0,0};
#pragma unroll 4
  for (int k = 0; k < K; k += 32) {
    short8 av0 = *(const short8*)(a0 + k);
    short8 av1 = *(const short8*)(a1 + k);
    short8 bv0 = *(const short8*)(b0 + k);
    short8 bv1 = *(const short8*)(b1 + k);
    acc00 = __builtin_amdgcn_mfma_f32_16x16x32_bf16(av0, bv0, acc00, 0, 0, 0);
    acc01 = __builtin_amdgcn_mfma_f32_16x16x32_bf16(av0, bv1, acc01, 0, 0, 0);
    acc10 = __builtin_amdgcn_mfma_f32_16x16x32_bf16(av1, bv0, acc10, 0, 0, 0);
    acc11 = __builtin_amdgcn_mfma_f32_16x16x32_bf16(av1, bv1, acc11, 0, 0, 0);
  }
  const float bia0 = bias[Nb + lm], bia1 = bias[Nb + 16 + lm];
#pragma unroll
  for (int r = 0; r < 4; ++r) {
    const int row0 = Mb + quad * 4 + r;
    C[(size_t)row0 * N + Nb + lm]            = acc00[r] + bia0;
    C[(size_t)row0 * N + Nb + 16 + lm]       = acc01[r] + bia1;
    C[(size_t)(row0 + 16) * N + Nb + lm]     = acc10[r] + bia0;
    C[(size_t)(row0 + 16) * N + Nb + 16 + lm] = acc11[r] + bia1;
  }
}

// ---------------- host ----------------
extern "C" void kernel_launch(void* const* d_in, const int* in_sizes, int n_in,
                              void* d_out, int out_size, void* d_ws, size_t ws_size,
                              hipStream_t stream) {
  const float* inputs = (const float*)d_in[0];
  const float* tdiff  = (const float*)d_in[1];
  // d_in[2] = seq_lens : unused by the reference
  const float* W_all = (const float*)d_in[3];
  const float* b_all = (const float*)d_in[4];
  const float* U_all = (const float*)d_in[5];
  const float* b_u   = (const float*)d_in[6];
  const float* W_d   = (const float*)d_in[7];
  const float* b_d   = (const float*)d_in[8];
  const float* W_out = (const float*)d_in[9];
  const float* b_out = (const float*)d_in[10];

  float* out = (float*)d_out;
  float* d_outputs = out;                                   // [B,S,O]
  float* d_hs = out + (size_t)B_ * S_ * O_;                 // [B,S,H]
  float* d_cs = d_hs + (size_t)B_ * S_ * H_;                // [B,S,H]

  char* ws = (char*)d_ws;
  size_t off = 0;
  auto alloc = [&](size_t bytes) {
    char* p = ws + off;
    off += (bytes + 255) & ~(size_t)255;
    return p;
  };
  u16* xbf      = (u16*)alloc((size_t)B_ * S_ * D_ * 2);        // 32 MB
  u16* hs_bf    = (u16*)alloc((size_t)B_ * S_ * H_ * 2);        // 64 MB
  u16* UallT    = (u16*)alloc((size_t)2048 * 512 * 2);
  u16* WallT    = (u16*)alloc((size_t)2048 * 256 * 2);
  u16* WdT      = (u16*)alloc((size_t)512 * 512 * 2);
  u16* WoutT    = (u16*)alloc((size_t)256 * 512 * 2);
  u16* h_state  = (u16*)alloc((size_t)2 * B_ * H_ * 2);
  u16* c_state  = (u16*)alloc((size_t)2 * B_ * H_ * 2);
  unsigned* bar = (unsigned*)alloc(4096);

  // zero initial state + barrier counters (ws is re-poisoned before every call)
  hipMemsetAsync(h_state, 0, (size_t)2 * B_ * H_ * 2, stream);
  hipMemsetAsync(c_state, 0, (size_t)2 * B_ * H_ * 2, stream);
  hipMemsetAsync(bar, 0, 4096, stream);

  cvt_bf16_vec<<<(B_ * S_ * D_ / 4 + 255) / 256, 256, 0, stream>>>(inputs, xbf, B_ * S_ * D_ / 4);
  transpose_cvt<<<(256 * 2048 + 255) / 256, 256, 0, stream>>>(W_all, WallT, 256, 2048);
  transpose_cvt<<<(512 * 2048 + 255) / 256, 256, 0, stream>>>(U_all, UallT, 512, 2048);
  transpose_cvt<<<(512 * 512 + 255) / 256, 256, 0, stream>>>(W_d, WdT, 512, 512);
  transpose_cvt<<<(512 * 256 + 255) / 256, 256, 0, stream>>>(W_out, WoutT, 512, 256);

  (void)hipFuncSetAttribute((const void*)tlstm_scan,
                            hipFuncAttributeMaxDynamicSharedMemorySize, (int)SCAN_SMEM);
  tlstm_scan<<<256, 320, SCAN_SMEM, stream>>>(xbf, tdiff, UallT, WallT, WdT,
                                              b_all, b_u, b_d, h_state, c_state,
                                              bar, d_hs, d_cs, hs_bf);
  gemm2<<<dim3(B_ * S_ / 64, O_ / 64), 256, 0, stream>>>(hs_bf, WoutT, b_out, d_outputs);
}